// Round 6
// baseline (500.234 us; speedup 1.0000x reference)
//
#include <hip/hip_runtime.h>
#include <stdint.h>

typedef unsigned short u16;
typedef unsigned int u32;
typedef __attribute__((ext_vector_type(8))) short short8;   // 8 bf16 (4 VGPRs)
typedef __attribute__((ext_vector_type(4))) float f32x4;    // MFMA acc
typedef __attribute__((ext_vector_type(4))) u32 u32x4;

#define CSTR 8   // cnt stride (ints): 32B per counter, probes per-line atomic serialization

__device__ __forceinline__ u16 f2bf(float f) {              // RNE f32->bf16
    u32 x = __float_as_uint(f);
    u32 r = x + 0x7FFFu + ((x >> 16) & 1u);
    return (u16)(r >> 16);
}
__device__ __forceinline__ u32 pack2bf(float a, float b) {
    return (u32)f2bf(a) | ((u32)f2bf(b) << 16);
}
__device__ __forceinline__ float bflo(u32 w) { return __uint_as_float(w << 16); }
__device__ __forceinline__ float bfhi(u32 w) { return __uint_as_float(w & 0xFFFF0000u); }

// ======================= K_A: movie-hist || conv || wprep =======================
// Blocks [0,egH): movie-direction hist+rank (1 atomic/edge; rank = atomic return).
// Blocks [egH,egH+cg): f32->bf16 feature conversion (rides in hist's shadow).
// Blocks [egH+cg, +64): weight prep (4 stacks x 64 units of 64 lanes).
struct WPtrs {
    const float* wl[4];
    const float* wr[4];
    u16* wout[4];
};

__global__ __launch_bounds__(256)
void prep_a(const int* __restrict__ src, const int* __restrict__ dst,
            int* __restrict__ cnt, int* __restrict__ rankm,
            int E, int nu, int nm,
            const float* __restrict__ xu, const float* __restrict__ xm,
            u32* __restrict__ xub, u32* __restrict__ xmb,
            int egH, int cg, WPtrs wp) {
    const int bid = blockIdx.x;
    const int tid = threadIdx.x;
    if (bid < egH) {
        const int e0 = bid * 1024 + tid;
        int sv[4], dv[4];
        bool ok[4];
#pragma unroll
        for (int k = 0; k < 4; ++k) {
            int e = e0 + k * 256;
            ok[k] = (e < E);
            if (ok[k]) { sv[k] = src[e]; dv[k] = dst[e]; }
        }
#pragma unroll
        for (int k = 0; k < 4; ++k) {
            int e = e0 + k * 256;
            if (ok[k]) {
                if ((unsigned)sv[k] < (unsigned)nu &&
                    (unsigned)dv[k] < (unsigned)nm) {
                    rankm[e] = atomicAdd(&cnt[(size_t)(nu + dv[k]) * CSTR], 1);
                } else {
                    rankm[e] = -1;
                }
            }
        }
    } else if (bid < egH + cg) {
        // ---- f32 [.][128] -> packed bf16 u32 [.][64]; 4 u32 per thread ----
        const int id = (bid - egH) * 1024 + tid * 4;
        const int nuc = nu * 64;
        const int tot = nuc + nm * 64;   // both multiples of 4: no straddle
        if (id < tot) {
            const float* fin;
            u32* fout;
            int rel;
            if (id < nuc) { fin = xu; fout = xub; rel = id; }
            else          { fin = xm; fout = xmb; rel = id - nuc; }
            float4 p0 = ((const float4*)fin)[(rel >> 1)];
            float4 p1 = ((const float4*)fin)[(rel >> 1) + 1];
            u32x4 o = { pack2bf(p0.x, p0.y), pack2bf(p0.z, p0.w),
                        pack2bf(p1.x, p1.y), pack2bf(p1.z, p1.w) };
            *(u32x4*)(fout + rel) = o;
        }
    } else {
        // ---- wprep: W_stack=[Wl;Wr] (256x128 f32) -> bf16 MFMA-B-fragment
        const int unit = (bid - egH - cg) * 4 + (tid >> 6);
        if (unit < 256) {
            const int stack = unit >> 6, r = unit & 63, t = r >> 3, s = r & 7;
            const int lane = tid & 63;
            const float* Wl = wp.wl[stack];
            const float* Wr = wp.wr[stack];
            u16* outw = wp.wout[stack];
            const int n = t * 16 + (lane & 15);
            const int k0 = s * 32 + (lane >> 4) * 8;
            u16 v[8];
#pragma unroll
            for (int j = 0; j < 8; ++j) {
                int k = k0 + j;
                float f = (k < 128) ? Wl[k * 128 + n] : Wr[(k - 128) * 128 + n];
                v[j] = f2bf(f);
            }
            *(short8*)(outw + ((size_t)(t * 8 + s) * 64 + lane) * 8) = *(short8*)v;
        }
    }
}

// ======================= K_B: fill_m || user-hist =======================
// Blocks [0,egF): movie-direction fill (scattered stores, no atomics).
// Blocks [egF,2egF): user-direction hist+rank (independent of fill_m).
__global__ __launch_bounds__(256)
void prep_b(const int* __restrict__ src, const int* __restrict__ dst,
            int* __restrict__ cnt, int* __restrict__ ranku,
            const int* __restrict__ rankm, const int* __restrict__ off,
            int* __restrict__ nbr, int E, int nu, int nm, int egF) {
    const int bid = blockIdx.x;
    const int tid = threadIdx.x;
    if (bid < egF) {
        // ---- fill_m: nbr[off[nu+d] + rankm[e]] = s ----
        const int e0 = bid * 1024 + tid;
        int sv[4], dv[4], rm[4];
#pragma unroll
        for (int k = 0; k < 4; ++k) {
            int e = e0 + k * 256;
            rm[k] = -1;
            if (e < E) {
                rm[k] = rankm[e];
                sv[k] = src[e]; dv[k] = dst[e];
            }
        }
#pragma unroll
        for (int k = 0; k < 4; ++k) {
            if (rm[k] >= 0) nbr[off[nu + dv[k]] + rm[k]] = sv[k];
        }
    } else {
        // ---- user-hist ----
        const int e0 = (bid - egF) * 1024 + tid;
        int sv[4], dv[4];
        bool ok[4];
#pragma unroll
        for (int k = 0; k < 4; ++k) {
            int e = e0 + k * 256;
            ok[k] = (e < E);
            if (ok[k]) { sv[k] = src[e]; dv[k] = dst[e]; }
        }
#pragma unroll
        for (int k = 0; k < 4; ++k) {
            int e = e0 + k * 256;
            if (ok[k]) {
                if ((unsigned)sv[k] < (unsigned)nu &&
                    (unsigned)dv[k] < (unsigned)nm) {
                    ranku[e] = atomicAdd(&cnt[(size_t)sv[k] * CSTR], 1);
                } else {
                    ranku[e] = -1;
                }
            }
        }
    }
}

// ======================= scans (strided cnt; addbase for movie=E) ==========
__global__ __launch_bounds__(256)
void scan_partial(const int* __restrict__ cnt, int* __restrict__ bsum, int n) {
    __shared__ int s[256];
    const int tid = threadIdx.x;
    int base = blockIdx.x * 4096 + tid * 16;
    int sum = 0;
#pragma unroll
    for (int k = 0; k < 16; ++k) {
        int i = base + k;
        if (i < n) sum += cnt[(size_t)i * CSTR];
    }
    s[tid] = sum;
    __syncthreads();
    for (int d = 128; d > 0; d >>= 1) {
        if (tid < d) s[tid] += s[tid + d];
        __syncthreads();
    }
    if (tid == 0) bsum[blockIdx.x] = s[0];
}

// Each block redoes the tiny (nb<=64) top-level prefix itself.
__global__ __launch_bounds__(256)
void scan_apply(const int* __restrict__ cnt, const int* __restrict__ bsum,
                int* __restrict__ off, int n, int nb, int addbase) {
    __shared__ int s[256];
    __shared__ int sb[64];
    __shared__ int pfx;
    const int tid = threadIdx.x;
    int base = blockIdx.x * 4096 + tid * 16;
    int v[16];
    int sum = 0;
#pragma unroll
    for (int k = 0; k < 16; ++k) {
        int i = base + k;
        v[k] = (i < n) ? cnt[(size_t)i * CSTR] : 0;
        sum += v[k];
    }
    s[tid] = sum;
    if (tid < 64) sb[tid] = (tid < nb) ? bsum[tid] : 0;
    __syncthreads();
    for (int d = 1; d < 256; d <<= 1) {
        int t = (tid >= d) ? s[tid - d] : 0;
        __syncthreads();
        s[tid] += t;
        __syncthreads();
    }
    if (tid == 0) {
        int p = 0;
        for (int b2 = 0; b2 < (int)blockIdx.x; ++b2) p += sb[b2];
        pfx = p;
        if ((int)blockIdx.x == nb - 1) off[n] = addbase + p + s[255];
    }
    __syncthreads();
    int run = addbase + pfx + s[tid] - sum;
#pragma unroll
    for (int k = 0; k < 16; ++k) {
        int i = base + k;
        if (i < n) off[i] = run;
        run += v[k];
    }
}

// ================= fused gather-mean + MFMA node update =================
// (round-5 proven body: slot-parallel gather, 16 nodes/block, 2 waves)
template <int L1>
__device__ __forceinline__ void fused_body(
    const u32* __restrict__ featb, const float* __restrict__ xf,
    const u32* __restrict__ xb, const int* __restrict__ off,
    const int* __restrict__ nbr, const u16* __restrict__ wt,
    const float* __restrict__ bias, void* __restrict__ outp, int N, int blk) {
    __shared__ u32 sVb[16][132];     // bf16 pairs: k<128 mean, k>=128 x; pad 4
    const int tid = threadIdx.x;
    const int lane = tid & 63;
    const int wave = tid >> 6;       // 0..1
    const int base = blk * 16;
    const int q = lane >> 4;         // node slot (phase1) / D-row quad (phase2)
    const int cl = lane & 15;        // channel group (phase1) / D col (phase2)

    // ---- phase 1: slot-parallel gather-mean (2 quads of 4 nodes / wave) ----
#pragma unroll
    for (int gg = 0; gg < 2; ++gg) {
        const int i = wave * 8 + gg * 4 + q;   // node-local index 0..15
        const int n = base + i;
        int b = 0, e2 = 0;
        if (n < N) { b = off[n]; e2 = off[n + 1]; }
        const int deg = e2 - b;
        float a0 = 0.f, a1 = 0.f, a2 = 0.f, a3 = 0.f;
        float a4 = 0.f, a5 = 0.f, a6 = 0.f, a7 = 0.f;
        for (int j = 0; j < deg; j += 4) {
            const int p = b + j;
            const int p1 = (p + 1 < e2) ? p + 1 : e2 - 1;
            const int p2 = (p + 2 < e2) ? p + 2 : e2 - 1;
            const int p3 = (p + 3 < e2) ? p + 3 : e2 - 1;
            const float m1 = (p + 1 < e2) ? 1.f : 0.f;
            const float m2 = (p + 2 < e2) ? 1.f : 0.f;
            const float m3 = (p + 3 < e2) ? 1.f : 0.f;
            const int g0 = nbr[p];
            const int g1 = nbr[p1];
            const int g2 = nbr[p2];
            const int g3 = nbr[p3];
            u32x4 v0 = *(const u32x4*)(featb + (size_t)g0 * 64 + cl * 4);
            u32x4 v1 = *(const u32x4*)(featb + (size_t)g1 * 64 + cl * 4);
            u32x4 v2 = *(const u32x4*)(featb + (size_t)g2 * 64 + cl * 4);
            u32x4 v3 = *(const u32x4*)(featb + (size_t)g3 * 64 + cl * 4);
            a0 += bflo(v0.x); a1 += bfhi(v0.x); a2 += bflo(v0.y); a3 += bfhi(v0.y);
            a4 += bflo(v0.z); a5 += bfhi(v0.z); a6 += bflo(v0.w); a7 += bfhi(v0.w);
            a0 = fmaf(bflo(v1.x), m1, a0); a1 = fmaf(bfhi(v1.x), m1, a1);
            a2 = fmaf(bflo(v1.y), m1, a2); a3 = fmaf(bfhi(v1.y), m1, a3);
            a4 = fmaf(bflo(v1.z), m1, a4); a5 = fmaf(bfhi(v1.z), m1, a5);
            a6 = fmaf(bflo(v1.w), m1, a6); a7 = fmaf(bfhi(v1.w), m1, a7);
            a0 = fmaf(bflo(v2.x), m2, a0); a1 = fmaf(bfhi(v2.x), m2, a1);
            a2 = fmaf(bflo(v2.y), m2, a2); a3 = fmaf(bfhi(v2.y), m2, a3);
            a4 = fmaf(bflo(v2.z), m2, a4); a5 = fmaf(bfhi(v2.z), m2, a5);
            a6 = fmaf(bflo(v2.w), m2, a6); a7 = fmaf(bfhi(v2.w), m2, a7);
            a0 = fmaf(bflo(v3.x), m3, a0); a1 = fmaf(bfhi(v3.x), m3, a1);
            a2 = fmaf(bflo(v3.y), m3, a2); a3 = fmaf(bfhi(v3.y), m3, a3);
            a4 = fmaf(bflo(v3.z), m3, a4); a5 = fmaf(bfhi(v3.z), m3, a5);
            a6 = fmaf(bflo(v3.w), m3, a6); a7 = fmaf(bfhi(v3.w), m3, a7);
        }
        const float inv = 1.0f / (float)(deg > 1 ? deg : 1);
        u32x4 o = { pack2bf(a0 * inv, a1 * inv), pack2bf(a2 * inv, a3 * inv),
                    pack2bf(a4 * inv, a5 * inv), pack2bf(a6 * inv, a7 * inv) };
        *(u32x4*)&sVb[i][cl * 4] = o;     // slot's 16 lanes = full 256B row
    }
    // ---- x staging (full-wave coalesced rows, 8 nodes/wave) ----
    for (int c = 0; c < 8; ++c) {
        const int i = wave * 8 + c;
        const int n = base + i;
        if (n < N) {
            if (L1) {
                const float2 xv = ((const float2*)xf)[(size_t)n * 64 + lane];
                sVb[i][64 + lane] = pack2bf(xv.x, xv.y);
            } else {
                sVb[i][64 + lane] = xb[(size_t)n * 64 + lane];
            }
        } else {
            sVb[i][64 + lane] = 0u;
        }
    }
    __syncthreads();

    // ---- phase 2: MFMA GEMM (16 nodes x 256 K x 128 out), 4 tiles/wave ----
    const int t0 = wave * 4;
    const u16* sVbu = (const u16*)sVb;  // row stride 264 ushort (528 B)
    const short8* wtp = (const short8*)wt;

    f32x4 acc0 = {0.f, 0.f, 0.f, 0.f};
    f32x4 acc1 = {0.f, 0.f, 0.f, 0.f};
    f32x4 acc2 = {0.f, 0.f, 0.f, 0.f};
    f32x4 acc3 = {0.f, 0.f, 0.f, 0.f};
#pragma unroll
    for (int s = 0; s < 8; ++s) {
        short8 a = *(const short8*)(sVbu + (size_t)cl * 264 + s * 32 + q * 8);
        short8 b0 = wtp[(size_t)((t0 + 0) * 8 + s) * 64 + lane];
        short8 b1 = wtp[(size_t)((t0 + 1) * 8 + s) * 64 + lane];
        short8 b2 = wtp[(size_t)((t0 + 2) * 8 + s) * 64 + lane];
        short8 b3 = wtp[(size_t)((t0 + 3) * 8 + s) * 64 + lane];
        acc0 = __builtin_amdgcn_mfma_f32_16x16x32_bf16(a, b0, acc0, 0, 0, 0);
        acc1 = __builtin_amdgcn_mfma_f32_16x16x32_bf16(a, b1, acc1, 0, 0, 0);
        acc2 = __builtin_amdgcn_mfma_f32_16x16x32_bf16(a, b2, acc2, 0, 0, 0);
        acc3 = __builtin_amdgcn_mfma_f32_16x16x32_bf16(a, b3, acc3, 0, 0, 0);
    }

    // ---- epilogue: D[m][n], col=lane&15, row=quad*4+reg ----
#pragma unroll
    for (int tt = 0; tt < 4; ++tt) {
        const f32x4& cc = tt == 0 ? acc0 : tt == 1 ? acc1 : tt == 2 ? acc2 : acc3;
        const int nn = (t0 + tt) * 16 + cl;
        const float bj = bias[nn];
#pragma unroll
        for (int r = 0; r < 4; ++r) {
            const int m = q * 4 + r;
            const int node = base + m;
            if (node < N) {
                float h = cc[r] + bj;
                if (L1) {
                    u16* ob = (u16*)outp;
                    float x0 = xf[(size_t)node * 128 + nn];   // L1-hot reload
                    ob[(size_t)node * 128 + nn] = f2bf(x0 + fmaxf(h, 0.f));
                } else {
                    float* o = (float*)outp;
                    o[(size_t)node * 128 + nn] = h;
                }
            }
        }
    }
}

// ======================= K_C: l1_movie || fill_u =======================
// Blocks [0,gm): L1 movie update (gathers xu_bf via movie CSR, writes rm_bf).
// Blocks [gm,gm+egF): fill_u (user nbr segments; hides under the gather).
// Disjoint nbr ranges: movie segs [E,2E) read, user segs [0,E) written.
__global__ __launch_bounds__(128, 8)
void l1movie_fillu(const u32* __restrict__ Abf, const float* __restrict__ xm,
                   const int* __restrict__ off, const int* __restrict__ nbr_r,
                   const u16* __restrict__ wt, const float* __restrict__ bias,
                   void* __restrict__ outp, int nm, int nu, int gm,
                   const int* __restrict__ src, const int* __restrict__ dst,
                   const int* __restrict__ ranku, int* __restrict__ nbr_w,
                   int E) {
    if ((int)blockIdx.x < gm) {
        fused_body<1>(Abf, xm, nullptr, off + nu, nbr_r, wt, bias, outp, nm,
                      blockIdx.x);
    } else {
        const int e0 = ((int)blockIdx.x - gm) * 1024 + (int)threadIdx.x;
        int sv[8], dv[8], ru[8];
#pragma unroll
        for (int k = 0; k < 8; ++k) {
            int e = e0 + k * 128;
            ru[k] = -1;
            if (e < E) {
                ru[k] = ranku[e];
                sv[k] = src[e]; dv[k] = dst[e];
            }
        }
#pragma unroll
        for (int k = 0; k < 8; ++k) {
            if (ru[k] >= 0) nbr_w[off[sv[k]] + ru[k]] = dv[k];
        }
    }
}

__global__ __launch_bounds__(128, 8)
void fused_l1(const u32* __restrict__ featb, const float* __restrict__ xf,
              const int* __restrict__ off, const int* __restrict__ nbr,
              const u16* __restrict__ wt, const float* __restrict__ bias,
              void* __restrict__ outp, int N) {
    fused_body<1>(featb, xf, nullptr, off, nbr, wt, bias, outp, N, blockIdx.x);
}

// Layer-2 pair merged (no aliasing: reads Abf+rmb only, writes d_out only).
__global__ __launch_bounds__(128, 8)
void fused_l2_dual(const u32* __restrict__ Abf, const u32* __restrict__ rmb,
                   const int* __restrict__ off, const int* __restrict__ nbr,
                   const u16* __restrict__ wtm, const u16* __restrict__ wtu,
                   const float* __restrict__ bm, const float* __restrict__ bu,
                   float* __restrict__ outm, float* __restrict__ outu,
                   int nm, int nu, int gm) {
    if ((int)blockIdx.x < gm)
        fused_body<0>(Abf, nullptr, rmb, off + nu, nbr, wtm, bm, outm, nm,
                      blockIdx.x);
    else
        fused_body<0>(rmb, nullptr, Abf, off, nbr, wtu, bu, outu, nu,
                      blockIdx.x - gm);
}

extern "C" void kernel_launch(void* const* d_in, const int* in_sizes, int n_in,
                              void* d_out, int out_size, void* d_ws, size_t ws_size,
                              hipStream_t stream) {
    const int nu = in_sizes[0] / 128;
    const int nm = in_sizes[1] / 128;
    const int E = in_sizes[2];

    const float* xu = (const float*)d_in[0];
    const float* xm = (const float*)d_in[1];
    const int* esrc = (const int*)d_in[2];
    const int* edst = (const int*)d_in[3];
    const float* Wl1_um = (const float*)d_in[4];
    const float* Wr1_um = (const float*)d_in[5];
    const float* Wl1_mu = (const float*)d_in[6];
    const float* Wr1_mu = (const float*)d_in[7];
    const float* Wl2_um = (const float*)d_in[8];
    const float* Wr2_um = (const float*)d_in[9];
    const float* Wl2_mu = (const float*)d_in[10];
    const float* Wr2_mu = (const float*)d_in[11];
    const float* b1_um = (const float*)d_in[12];
    const float* b1_mu = (const float*)d_in[13];
    const float* b2_um = (const float*)d_in[14];
    const float* b2_mu = (const float*)d_in[15];

    float* out_u = (float*)d_out;
    float* out_m = out_u + (size_t)nu * 128;

    // ---- workspace layout (~56.5 MB; >=62 MB available) ----
    const int ntot = nu + nm;
    int* cnt = (int*)d_ws;                     // ntot * CSTR (32B-padded)
    int* off = cnt + (size_t)ntot * CSTR;      // ntot+1
    int* bsum = off + ntot + 1;                // 64
    int* ranku = bsum + 64;                    // E
    int* rankm = ranku + E;                    // E
    int* nbr = rankm + E;                      // 2E
    size_t int_bytes = (size_t)((nbr + 2 * (size_t)E) - (int*)d_ws) * 4;
    size_t wt_off = (int_bytes + 63) & ~(size_t)63;   // 16B-align for short8
    u16* wt1_um = (u16*)((char*)d_ws + wt_off);       // 4 stacks x 32768 u16
    u16* wt1_mu = wt1_um + 32768;
    u16* wt2_um = wt1_mu + 32768;
    u16* wt2_mu = wt2_um + 32768;
    // bf16 feature buffers. Abf holds xu_bf for layer 1, then is overwritten
    // with ru_bf by the L1-user dispatch (xu_bf's last consumer, L1-movie,
    // completes first in stream order).
    u32* Abf = (u32*)((char*)d_ws + wt_off + 4 * 65536);  // nu*64
    u32* xmb = Abf + (size_t)nu * 64;                     // nm*64
    u32* rmb = xmb + (size_t)nm * 64;                     // nm*64

    const int egH = (E + 1023) / 1024;         // 256-thr, 4 edges/thread
    const int egF = (E + 1023) / 1024;         // fill grids
    const int cg = (ntot * 64 + 1023) / 1024;
    const int NBm = (nm + 4095) / 4096;        // <=64
    const int NBu = (nu + 4095) / 4096;        // <=64

    WPtrs wp;
    wp.wl[0] = Wl1_um; wp.wr[0] = Wr1_um; wp.wout[0] = wt1_um;
    wp.wl[1] = Wl1_mu; wp.wr[1] = Wr1_mu; wp.wout[1] = wt1_mu;
    wp.wl[2] = Wl2_um; wp.wr[2] = Wr2_um; wp.wout[2] = wt2_um;
    wp.wl[3] = Wl2_mu; wp.wr[3] = Wr2_mu; wp.wout[3] = wt2_mu;

    const int gm = (nm + 15) / 16;
    const int gu = (nu + 15) / 16;

    // ---- pipeline (round-6): overlap CSR build with gather work ----
    hipMemsetAsync(cnt, 0, (size_t)ntot * CSTR * 4, stream);
    // K_A: movie-hist || conv || wprep
    prep_a<<<egH + cg + 64, 256, 0, stream>>>(
        esrc, edst, cnt, rankm, E, nu, nm, xu, xm, Abf, xmb, egH, cg, wp);
    // scan movie counts -> off[nu..ntot], based at E (movie segs in [E,2E))
    scan_partial<<<NBm, 256, 0, stream>>>(cnt + (size_t)nu * CSTR, bsum, nm);
    scan_apply<<<NBm, 256, 0, stream>>>(cnt + (size_t)nu * CSTR, bsum,
                                        off + nu, nm, NBm, E);
    // K_B: fill_m || user-hist
    prep_b<<<2 * egF, 256, 0, stream>>>(esrc, edst, cnt, ranku, rankm, off,
                                        nbr, E, nu, nm, egF);
    // scan user counts -> off[0..nu], off[nu]=E
    scan_partial<<<NBu, 256, 0, stream>>>(cnt, bsum, nu);
    scan_apply<<<NBu, 256, 0, stream>>>(cnt, bsum, off, nu, NBu, 0);
    // K_C: l1_movie (gather xu_bf -> rm_bf) || fill_u
    l1movie_fillu<<<gm + egF, 128, 0, stream>>>(
        Abf, xm, off, nbr, wt1_um, b1_um, rmb, nm, nu, gm,
        esrc, edst, ranku, nbr, E);
    // K_D: l1_user (gather xm_bf, x=xu, write ru_bf into Abf; xu_bf dead)
    fused_l1<<<gu, 128, 0, stream>>>(xmb, xu, off, nbr, wt1_mu, b1_mu,
                                     Abf, nu);
    // K_E: layer 2 merged (reads Abf/rmb only; writes d_out only)
    fused_l2_dual<<<gm + gu, 128, 0, stream>>>(
        Abf, rmb, off, nbr, wt2_um, wt2_mu, b2_um, b2_mu, out_m, out_u,
        nm, nu, gm);
}

// Round 7
// 480.689 us; speedup vs baseline: 1.0407x; 1.0407x over previous
//
#include <hip/hip_runtime.h>
#include <stdint.h>

typedef unsigned short u16;
typedef unsigned int u32;
typedef __attribute__((ext_vector_type(8))) short short8;   // 8 bf16 (4 VGPRs)
typedef __attribute__((ext_vector_type(4))) float f32x4;    // MFMA acc
typedef __attribute__((ext_vector_type(4))) u32 u32x4;

#define CSTR 8   // cnt stride (ints): 32B per counter (atomic-line spreading)

__device__ __forceinline__ u16 f2bf(float f) {              // RNE f32->bf16
    u32 x = __float_as_uint(f);
    u32 r = x + 0x7FFFu + ((x >> 16) & 1u);
    return (u16)(r >> 16);
}
__device__ __forceinline__ u32 pack2bf(float a, float b) {
    return (u32)f2bf(a) | ((u32)f2bf(b) << 16);
}
__device__ __forceinline__ float bflo(u32 w) { return __uint_as_float(w << 16); }
__device__ __forceinline__ float bfhi(u32 w) { return __uint_as_float(w & 0xFFFF0000u); }

// ======================= prep: both-dir hist || conv || wprep ===============
// Blocks [0,egH): hist+rank both directions (2 atomics/edge, ONE edge read —
// round-5 proven; round-6 split into two passes regressed).
// Blocks [egH,egH+cg): f32->bf16 feature conversion (rides in hist's shadow).
// Blocks [egH+cg, +64): weight prep (4 stacks x 64 units of 64 lanes).
struct WPtrs {
    const float* wl[4];
    const float* wr[4];
    u16* wout[4];
};

__global__ __launch_bounds__(256)
void prep_kernel(const int* __restrict__ src, const int* __restrict__ dst,
                 int* __restrict__ cnt, int* __restrict__ ranku,
                 int* __restrict__ rankm, int E, int nu, int nm,
                 const float* __restrict__ xu, const float* __restrict__ xm,
                 u32* __restrict__ xub, u32* __restrict__ xmb,
                 int egH, int cg, WPtrs wp) {
    const int bid = blockIdx.x;
    const int tid = threadIdx.x;
    if (bid < egH) {
        const int e0 = bid * 1024 + tid;
        int sv[4], dv[4];
        bool ok[4];
#pragma unroll
        for (int k = 0; k < 4; ++k) {
            int e = e0 + k * 256;
            ok[k] = (e < E);
            if (ok[k]) { sv[k] = src[e]; dv[k] = dst[e]; }
        }
#pragma unroll
        for (int k = 0; k < 4; ++k) {
            int e = e0 + k * 256;
            if (ok[k]) {
                if ((unsigned)sv[k] < (unsigned)nu &&
                    (unsigned)dv[k] < (unsigned)nm) {
                    ranku[e] = atomicAdd(&cnt[(size_t)sv[k] * CSTR], 1);
                    rankm[e] = atomicAdd(&cnt[(size_t)(nu + dv[k]) * CSTR], 1);
                } else {
                    ranku[e] = -1;
                }
            }
        }
    } else if (bid < egH + cg) {
        // ---- f32 [.][128] -> packed bf16 u32 [.][64]; 4 u32 per thread ----
        const int id = (bid - egH) * 1024 + tid * 4;
        const int nuc = nu * 64;
        const int tot = nuc + nm * 64;   // both multiples of 4: no straddle
        if (id < tot) {
            const float* fin;
            u32* fout;
            int rel;
            if (id < nuc) { fin = xu; fout = xub; rel = id; }
            else          { fin = xm; fout = xmb; rel = id - nuc; }
            float4 p0 = ((const float4*)fin)[(rel >> 1)];
            float4 p1 = ((const float4*)fin)[(rel >> 1) + 1];
            u32x4 o = { pack2bf(p0.x, p0.y), pack2bf(p0.z, p0.w),
                        pack2bf(p1.x, p1.y), pack2bf(p1.z, p1.w) };
            *(u32x4*)(fout + rel) = o;
        }
    } else {
        // ---- wprep: W_stack=[Wl;Wr] (256x128 f32) -> bf16 MFMA-B-fragment
        const int unit = (bid - egH - cg) * 4 + (tid >> 6);
        if (unit < 256) {
            const int stack = unit >> 6, r = unit & 63, t = r >> 3, s = r & 7;
            const int lane = tid & 63;
            const float* Wl = wp.wl[stack];
            const float* Wr = wp.wr[stack];
            u16* outw = wp.wout[stack];
            const int n = t * 16 + (lane & 15);
            const int k0 = s * 32 + (lane >> 4) * 8;
            u16 v[8];
#pragma unroll
            for (int j = 0; j < 8; ++j) {
                int k = k0 + j;
                float f = (k < 128) ? Wl[k * 128 + n] : Wr[(k - 128) * 128 + n];
                v[j] = f2bf(f);
            }
            *(short8*)(outw + ((size_t)(t * 8 + s) * 64 + lane) * 8) = *(short8*)v;
        }
    }
}

// ======================= scans (strided cnt; addbase for movie=E) ==========
__global__ __launch_bounds__(256)
void scan_partial(const int* __restrict__ cnt, int* __restrict__ bsum, int n) {
    __shared__ int s[256];
    const int tid = threadIdx.x;
    int base = blockIdx.x * 4096 + tid * 16;
    int sum = 0;
#pragma unroll
    for (int k = 0; k < 16; ++k) {
        int i = base + k;
        if (i < n) sum += cnt[(size_t)i * CSTR];
    }
    s[tid] = sum;
    __syncthreads();
    for (int d = 128; d > 0; d >>= 1) {
        if (tid < d) s[tid] += s[tid + d];
        __syncthreads();
    }
    if (tid == 0) bsum[blockIdx.x] = s[0];
}

// Each block redoes the tiny (nb<=64) top-level prefix itself.
__global__ __launch_bounds__(256)
void scan_apply(const int* __restrict__ cnt, const int* __restrict__ bsum,
                int* __restrict__ off, int n, int nb, int addbase) {
    __shared__ int s[256];
    __shared__ int sb[64];
    __shared__ int pfx;
    const int tid = threadIdx.x;
    int base = blockIdx.x * 4096 + tid * 16;
    int v[16];
    int sum = 0;
#pragma unroll
    for (int k = 0; k < 16; ++k) {
        int i = base + k;
        v[k] = (i < n) ? cnt[(size_t)i * CSTR] : 0;
        sum += v[k];
    }
    s[tid] = sum;
    if (tid < 64) sb[tid] = (tid < nb) ? bsum[tid] : 0;
    __syncthreads();
    for (int d = 1; d < 256; d <<= 1) {
        int t = (tid >= d) ? s[tid - d] : 0;
        __syncthreads();
        s[tid] += t;
        __syncthreads();
    }
    if (tid == 0) {
        int p = 0;
        for (int b2 = 0; b2 < (int)blockIdx.x; ++b2) p += sb[b2];
        pfx = p;
        if ((int)blockIdx.x == nb - 1) off[n] = addbase + p + s[255];
    }
    __syncthreads();
    int run = addbase + pfx + s[tid] - sum;
#pragma unroll
    for (int k = 0; k < 16; ++k) {
        int i = base + k;
        if (i < n) off[i] = run;
        run += v[k];
    }
}

// ============ fill_m: movie-direction fill (no atomics) ============
__global__ __launch_bounds__(256)
void fill_m(const int* __restrict__ src, const int* __restrict__ dst,
            const int* __restrict__ rankm, const int* __restrict__ off,
            int* __restrict__ nbr, int E, int nu) {
    const int e0 = blockIdx.x * 1024 + threadIdx.x;
    int sv[4], dv[4], rm[4];
#pragma unroll
    for (int k = 0; k < 4; ++k) {
        int e = e0 + k * 256;
        rm[k] = -1;
        if (e < E) {
            rm[k] = rankm[e];
            sv[k] = src[e]; dv[k] = dst[e];
        }
    }
#pragma unroll
    for (int k = 0; k < 4; ++k) {
        if (rm[k] >= 0) nbr[off[nu + dv[k]] + rm[k]] = sv[k];
    }
}

// ================= fused gather-mean + MFMA node update =================
// (round-5 proven body: slot-parallel gather, 16 nodes/block, 2 waves)
template <int L1>
__device__ __forceinline__ void fused_body(
    const u32* __restrict__ featb, const float* __restrict__ xf,
    const u32* __restrict__ xb, const int* __restrict__ off,
    const int* __restrict__ nbr, const u16* __restrict__ wt,
    const float* __restrict__ bias, void* __restrict__ outp, int N, int blk) {
    __shared__ u32 sVb[16][132];     // bf16 pairs: k<128 mean, k>=128 x; pad 4
    const int tid = threadIdx.x;
    const int lane = tid & 63;
    const int wave = tid >> 6;       // 0..1
    const int base = blk * 16;
    const int q = lane >> 4;         // node slot (phase1) / D-row quad (phase2)
    const int cl = lane & 15;        // channel group (phase1) / D col (phase2)

    // ---- phase 1: slot-parallel gather-mean (2 quads of 4 nodes / wave) ----
#pragma unroll
    for (int gg = 0; gg < 2; ++gg) {
        const int i = wave * 8 + gg * 4 + q;   // node-local index 0..15
        const int n = base + i;
        int b = 0, e2 = 0;
        if (n < N) { b = off[n]; e2 = off[n + 1]; }
        const int deg = e2 - b;
        float a0 = 0.f, a1 = 0.f, a2 = 0.f, a3 = 0.f;
        float a4 = 0.f, a5 = 0.f, a6 = 0.f, a7 = 0.f;
        for (int j = 0; j < deg; j += 4) {
            const int p = b + j;
            const int p1 = (p + 1 < e2) ? p + 1 : e2 - 1;
            const int p2 = (p + 2 < e2) ? p + 2 : e2 - 1;
            const int p3 = (p + 3 < e2) ? p + 3 : e2 - 1;
            const float m1 = (p + 1 < e2) ? 1.f : 0.f;
            const float m2 = (p + 2 < e2) ? 1.f : 0.f;
            const float m3 = (p + 3 < e2) ? 1.f : 0.f;
            const int g0 = nbr[p];
            const int g1 = nbr[p1];
            const int g2 = nbr[p2];
            const int g3 = nbr[p3];
            u32x4 v0 = *(const u32x4*)(featb + (size_t)g0 * 64 + cl * 4);
            u32x4 v1 = *(const u32x4*)(featb + (size_t)g1 * 64 + cl * 4);
            u32x4 v2 = *(const u32x4*)(featb + (size_t)g2 * 64 + cl * 4);
            u32x4 v3 = *(const u32x4*)(featb + (size_t)g3 * 64 + cl * 4);
            a0 += bflo(v0.x); a1 += bfhi(v0.x); a2 += bflo(v0.y); a3 += bfhi(v0.y);
            a4 += bflo(v0.z); a5 += bfhi(v0.z); a6 += bflo(v0.w); a7 += bfhi(v0.w);
            a0 = fmaf(bflo(v1.x), m1, a0); a1 = fmaf(bfhi(v1.x), m1, a1);
            a2 = fmaf(bflo(v1.y), m1, a2); a3 = fmaf(bfhi(v1.y), m1, a3);
            a4 = fmaf(bflo(v1.z), m1, a4); a5 = fmaf(bfhi(v1.z), m1, a5);
            a6 = fmaf(bflo(v1.w), m1, a6); a7 = fmaf(bfhi(v1.w), m1, a7);
            a0 = fmaf(bflo(v2.x), m2, a0); a1 = fmaf(bfhi(v2.x), m2, a1);
            a2 = fmaf(bflo(v2.y), m2, a2); a3 = fmaf(bfhi(v2.y), m2, a3);
            a4 = fmaf(bflo(v2.z), m2, a4); a5 = fmaf(bfhi(v2.z), m2, a5);
            a6 = fmaf(bflo(v2.w), m2, a6); a7 = fmaf(bfhi(v2.w), m2, a7);
            a0 = fmaf(bflo(v3.x), m3, a0); a1 = fmaf(bfhi(v3.x), m3, a1);
            a2 = fmaf(bflo(v3.y), m3, a2); a3 = fmaf(bfhi(v3.y), m3, a3);
            a4 = fmaf(bflo(v3.z), m3, a4); a5 = fmaf(bfhi(v3.z), m3, a5);
            a6 = fmaf(bflo(v3.w), m3, a6); a7 = fmaf(bfhi(v3.w), m3, a7);
        }
        const float inv = 1.0f / (float)(deg > 1 ? deg : 1);
        u32x4 o = { pack2bf(a0 * inv, a1 * inv), pack2bf(a2 * inv, a3 * inv),
                    pack2bf(a4 * inv, a5 * inv), pack2bf(a6 * inv, a7 * inv) };
        *(u32x4*)&sVb[i][cl * 4] = o;     // slot's 16 lanes = full 256B row
    }
    // ---- x staging (full-wave coalesced rows, 8 nodes/wave) ----
    for (int c = 0; c < 8; ++c) {
        const int i = wave * 8 + c;
        const int n = base + i;
        if (n < N) {
            if (L1) {
                const float2 xv = ((const float2*)xf)[(size_t)n * 64 + lane];
                sVb[i][64 + lane] = pack2bf(xv.x, xv.y);
            } else {
                sVb[i][64 + lane] = xb[(size_t)n * 64 + lane];
            }
        } else {
            sVb[i][64 + lane] = 0u;
        }
    }
    __syncthreads();

    // ---- phase 2: MFMA GEMM (16 nodes x 256 K x 128 out), 4 tiles/wave ----
    const int t0 = wave * 4;
    const u16* sVbu = (const u16*)sVb;  // row stride 264 ushort (528 B)
    const short8* wtp = (const short8*)wt;

    f32x4 acc0 = {0.f, 0.f, 0.f, 0.f};
    f32x4 acc1 = {0.f, 0.f, 0.f, 0.f};
    f32x4 acc2 = {0.f, 0.f, 0.f, 0.f};
    f32x4 acc3 = {0.f, 0.f, 0.f, 0.f};
#pragma unroll
    for (int s = 0; s < 8; ++s) {
        short8 a = *(const short8*)(sVbu + (size_t)cl * 264 + s * 32 + q * 8);
        short8 b0 = wtp[(size_t)((t0 + 0) * 8 + s) * 64 + lane];
        short8 b1 = wtp[(size_t)((t0 + 1) * 8 + s) * 64 + lane];
        short8 b2 = wtp[(size_t)((t0 + 2) * 8 + s) * 64 + lane];
        short8 b3 = wtp[(size_t)((t0 + 3) * 8 + s) * 64 + lane];
        acc0 = __builtin_amdgcn_mfma_f32_16x16x32_bf16(a, b0, acc0, 0, 0, 0);
        acc1 = __builtin_amdgcn_mfma_f32_16x16x32_bf16(a, b1, acc1, 0, 0, 0);
        acc2 = __builtin_amdgcn_mfma_f32_16x16x32_bf16(a, b2, acc2, 0, 0, 0);
        acc3 = __builtin_amdgcn_mfma_f32_16x16x32_bf16(a, b3, acc3, 0, 0, 0);
    }

    // ---- epilogue: D[m][n], col=lane&15, row=quad*4+reg ----
#pragma unroll
    for (int tt = 0; tt < 4; ++tt) {
        const f32x4& cc = tt == 0 ? acc0 : tt == 1 ? acc1 : tt == 2 ? acc2 : acc3;
        const int nn = (t0 + tt) * 16 + cl;
        const float bj = bias[nn];
#pragma unroll
        for (int r = 0; r < 4; ++r) {
            const int m = q * 4 + r;
            const int node = base + m;
            if (node < N) {
                float h = cc[r] + bj;
                if (L1) {
                    u16* ob = (u16*)outp;
                    float x0 = xf[(size_t)node * 128 + nn];   // L1-hot reload
                    ob[(size_t)node * 128 + nn] = f2bf(x0 + fmaxf(h, 0.f));
                } else {
                    float* o = (float*)outp;
                    o[(size_t)node * 128 + nn] = h;
                }
            }
        }
    }
}

// ======================= K_C: l1_movie || fill_u =======================
// Blocks [0,gm): L1 movie update (gathers xu_bf via movie CSR, writes rm_bf).
// Blocks [gm,gm+egF): fill_u (user nbr segments; hides under the gather).
// Disjoint nbr ranges: movie segs [E,2E) read, user segs [0,E) written.
__global__ __launch_bounds__(128, 8)
void l1movie_fillu(const u32* __restrict__ Abf, const float* __restrict__ xm,
                   const int* __restrict__ off, const int* __restrict__ nbr_r,
                   const u16* __restrict__ wt, const float* __restrict__ bias,
                   void* __restrict__ outp, int nm, int nu, int gm,
                   const int* __restrict__ src, const int* __restrict__ dst,
                   const int* __restrict__ ranku, int* __restrict__ nbr_w,
                   int E) {
    if ((int)blockIdx.x < gm) {
        fused_body<1>(Abf, xm, nullptr, off + nu, nbr_r, wt, bias, outp, nm,
                      blockIdx.x);
    } else {
        const int e0 = ((int)blockIdx.x - gm) * 1024 + (int)threadIdx.x;
        int sv[8], dv[8], ru[8];
#pragma unroll
        for (int k = 0; k < 8; ++k) {
            int e = e0 + k * 128;
            ru[k] = -1;
            if (e < E) {
                ru[k] = ranku[e];
                sv[k] = src[e]; dv[k] = dst[e];
            }
        }
#pragma unroll
        for (int k = 0; k < 8; ++k) {
            if (ru[k] >= 0) nbr_w[off[sv[k]] + ru[k]] = dv[k];
        }
    }
}

__global__ __launch_bounds__(128, 8)
void fused_l1(const u32* __restrict__ featb, const float* __restrict__ xf,
              const int* __restrict__ off, const int* __restrict__ nbr,
              const u16* __restrict__ wt, const float* __restrict__ bias,
              void* __restrict__ outp, int N) {
    fused_body<1>(featb, xf, nullptr, off, nbr, wt, bias, outp, N, blockIdx.x);
}

// Layer-2 pair merged (no aliasing: reads Abf+rmb only, writes d_out only).
__global__ __launch_bounds__(128, 8)
void fused_l2_dual(const u32* __restrict__ Abf, const u32* __restrict__ rmb,
                   const int* __restrict__ off, const int* __restrict__ nbr,
                   const u16* __restrict__ wtm, const u16* __restrict__ wtu,
                   const float* __restrict__ bm, const float* __restrict__ bu,
                   float* __restrict__ outm, float* __restrict__ outu,
                   int nm, int nu, int gm) {
    if ((int)blockIdx.x < gm)
        fused_body<0>(Abf, nullptr, rmb, off + nu, nbr, wtm, bm, outm, nm,
                      blockIdx.x);
    else
        fused_body<0>(rmb, nullptr, Abf, off, nbr, wtu, bu, outu, nu,
                      blockIdx.x - gm);
}

extern "C" void kernel_launch(void* const* d_in, const int* in_sizes, int n_in,
                              void* d_out, int out_size, void* d_ws, size_t ws_size,
                              hipStream_t stream) {
    const int nu = in_sizes[0] / 128;
    const int nm = in_sizes[1] / 128;
    const int E = in_sizes[2];

    const float* xu = (const float*)d_in[0];
    const float* xm = (const float*)d_in[1];
    const int* esrc = (const int*)d_in[2];
    const int* edst = (const int*)d_in[3];
    const float* Wl1_um = (const float*)d_in[4];
    const float* Wr1_um = (const float*)d_in[5];
    const float* Wl1_mu = (const float*)d_in[6];
    const float* Wr1_mu = (const float*)d_in[7];
    const float* Wl2_um = (const float*)d_in[8];
    const float* Wr2_um = (const float*)d_in[9];
    const float* Wl2_mu = (const float*)d_in[10];
    const float* Wr2_mu = (const float*)d_in[11];
    const float* b1_um = (const float*)d_in[12];
    const float* b1_mu = (const float*)d_in[13];
    const float* b2_um = (const float*)d_in[14];
    const float* b2_mu = (const float*)d_in[15];

    float* out_u = (float*)d_out;
    float* out_m = out_u + (size_t)nu * 128;

    // ---- workspace layout (~56.5 MB; >=62 MB available) ----
    const int ntot = nu + nm;
    int* cnt = (int*)d_ws;                     // ntot * CSTR (32B-padded)
    int* off = cnt + (size_t)ntot * CSTR;      // ntot+1
    int* bsum = off + ntot + 1;                // 64
    int* ranku = bsum + 64;                    // E
    int* rankm = ranku + E;                    // E
    int* nbr = rankm + E;                      // 2E
    size_t int_bytes = (size_t)((nbr + 2 * (size_t)E) - (int*)d_ws) * 4;
    size_t wt_off = (int_bytes + 63) & ~(size_t)63;   // 16B-align for short8
    u16* wt1_um = (u16*)((char*)d_ws + wt_off);       // 4 stacks x 32768 u16
    u16* wt1_mu = wt1_um + 32768;
    u16* wt2_um = wt1_mu + 32768;
    u16* wt2_mu = wt2_um + 32768;
    // bf16 feature buffers. Abf holds xu_bf for layer 1, then is overwritten
    // with ru_bf by the L1-user dispatch (xu_bf's last consumer, L1-movie,
    // completes first in stream order).
    u32* Abf = (u32*)((char*)d_ws + wt_off + 4 * 65536);  // nu*64
    u32* xmb = Abf + (size_t)nu * 64;                     // nm*64
    u32* rmb = xmb + (size_t)nm * 64;                     // nm*64

    const int egH = (E + 1023) / 1024;         // 256-thr, 4 edges/thread
    const int egF = (E + 1023) / 1024;
    const int cg = (ntot * 64 + 1023) / 1024;
    const int NBm = (nm + 4095) / 4096;        // <=64
    const int NBu = (nu + 4095) / 4096;        // <=64

    WPtrs wp;
    wp.wl[0] = Wl1_um; wp.wr[0] = Wr1_um; wp.wout[0] = wt1_um;
    wp.wl[1] = Wl1_mu; wp.wr[1] = Wr1_mu; wp.wout[1] = wt1_mu;
    wp.wl[2] = Wl2_um; wp.wr[2] = Wr2_um; wp.wout[2] = wt2_um;
    wp.wl[3] = Wl2_mu; wp.wr[3] = Wr2_mu; wp.wout[3] = wt2_mu;

    const int gm = (nm + 15) / 16;
    const int gu = (nu + 15) / 16;

    // ---- pipeline (round-7): combined hist; fill_u hidden under l1_movie ---
    hipMemsetAsync(cnt, 0, (size_t)ntot * CSTR * 4, stream);
    // prep: both-dir hist+rank || conv || wprep (one edge-list pass)
    prep_kernel<<<egH + cg + 64, 256, 0, stream>>>(
        esrc, edst, cnt, ranku, rankm, E, nu, nm, xu, xm, Abf, xmb, egH, cg, wp);
    // scans: movie counts -> off[nu..ntot] (base E); user counts -> off[0..nu]
    scan_partial<<<NBm, 256, 0, stream>>>(cnt + (size_t)nu * CSTR, bsum, nm);
    scan_apply<<<NBm, 256, 0, stream>>>(cnt + (size_t)nu * CSTR, bsum,
                                        off + nu, nm, NBm, E);
    scan_partial<<<NBu, 256, 0, stream>>>(cnt, bsum, nu);
    scan_apply<<<NBu, 256, 0, stream>>>(cnt, bsum, off, nu, NBu, 0);
    // fill movie segments only (user fill rides inside K_C)
    fill_m<<<egF, 256, 0, stream>>>(esrc, edst, rankm, off, nbr, E, nu);
    // K_C: l1_movie (gather xu_bf -> rm_bf) || fill_u
    l1movie_fillu<<<gm + egF, 128, 0, stream>>>(
        Abf, xm, off, nbr, wt1_um, b1_um, rmb, nm, nu, gm,
        esrc, edst, ranku, nbr, E);
    // l1_user (gather xm_bf, x=xu, write ru_bf into Abf; xu_bf dead)
    fused_l1<<<gu, 128, 0, stream>>>(xmb, xu, off, nbr, wt1_mu, b1_mu,
                                     Abf, nu);
    // layer 2 merged (reads Abf/rmb only; writes d_out only)
    fused_l2_dual<<<gm + gu, 128, 0, stream>>>(
        Abf, rmb, off, nbr, wt2_um, wt2_mu, b2_um, b2_mu, out_m, out_u,
        nm, nu, gm);
}

// Round 8
// 478.395 us; speedup vs baseline: 1.0457x; 1.0048x over previous
//
#include <hip/hip_runtime.h>
#include <stdint.h>

typedef unsigned short u16;
typedef unsigned int u32;
typedef __attribute__((ext_vector_type(8))) short short8;   // 8 bf16 (4 VGPRs)
typedef __attribute__((ext_vector_type(4))) float f32x4;    // MFMA acc
typedef __attribute__((ext_vector_type(4))) u32 u32x4;

#define CSTR 8   // cnt stride (ints): 32B per counter (neutral per round-7 probe)

__device__ __forceinline__ u16 f2bf(float f) {              // RNE f32->bf16
    u32 x = __float_as_uint(f);
    u32 r = x + 0x7FFFu + ((x >> 16) & 1u);
    return (u16)(r >> 16);
}
__device__ __forceinline__ u32 pack2bf(float a, float b) {
    return (u32)f2bf(a) | ((u32)f2bf(b) << 16);
}
__device__ __forceinline__ float bflo(u32 w) { return __uint_as_float(w << 16); }
__device__ __forceinline__ float bfhi(u32 w) { return __uint_as_float(w & 0xFFFF0000u); }

// ======================= K1: both-dir hist || wprep =======================
// Blocks [0,egH): hist+rank both directions (2 atomics/edge, one edge read).
// Blocks [egH,egH+64): weight prep. conv moved to K4 (round-8): the atomic
// kernel only grants leftover issue slots, stretching prep 87->109; fill_m's
// scatter phase hides streaming conv much better.
struct WPtrs {
    const float* wl[4];
    const float* wr[4];
    u16* wout[4];
};

__global__ __launch_bounds__(256)
void hist_wprep(const int* __restrict__ src, const int* __restrict__ dst,
                int* __restrict__ cnt, int* __restrict__ ranku,
                int* __restrict__ rankm, int E, int nu, int nm,
                int egH, WPtrs wp) {
    const int bid = blockIdx.x;
    const int tid = threadIdx.x;
    if (bid < egH) {
        const int e0 = bid * 1024 + tid;
        int sv[4], dv[4];
        bool ok[4];
#pragma unroll
        for (int k = 0; k < 4; ++k) {
            int e = e0 + k * 256;
            ok[k] = (e < E);
            if (ok[k]) { sv[k] = src[e]; dv[k] = dst[e]; }
        }
#pragma unroll
        for (int k = 0; k < 4; ++k) {
            int e = e0 + k * 256;
            if (ok[k]) {
                if ((unsigned)sv[k] < (unsigned)nu &&
                    (unsigned)dv[k] < (unsigned)nm) {
                    ranku[e] = atomicAdd(&cnt[(size_t)sv[k] * CSTR], 1);
                    rankm[e] = atomicAdd(&cnt[(size_t)(nu + dv[k]) * CSTR], 1);
                } else {
                    ranku[e] = -1;
                }
            }
        }
    } else {
        // ---- wprep: W_stack=[Wl;Wr] (256x128 f32) -> bf16 MFMA-B-fragment
        const int unit = (bid - egH) * 4 + (tid >> 6);
        if (unit < 256) {
            const int stack = unit >> 6, r = unit & 63, t = r >> 3, s = r & 7;
            const int lane = tid & 63;
            const float* Wl = wp.wl[stack];
            const float* Wr = wp.wr[stack];
            u16* outw = wp.wout[stack];
            const int n = t * 16 + (lane & 15);
            const int k0 = s * 32 + (lane >> 4) * 8;
            u16 v[8];
#pragma unroll
            for (int j = 0; j < 8; ++j) {
                int k = k0 + j;
                float f = (k < 128) ? Wl[k * 128 + n] : Wr[(k - 128) * 128 + n];
                v[j] = f2bf(f);
            }
            *(short8*)(outw + ((size_t)(t * 8 + s) * 64 + lane) * 8) = *(short8*)v;
        }
    }
}

// ============ K2/K3: fused scans (movie: bsum[0..64), user: bsum[64..128)) ==
__global__ __launch_bounds__(256)
void scan_partial2(const int* __restrict__ cnt, int* __restrict__ bsum,
                   int nu, int nm, int NBm) {
    __shared__ int s[256];
    const int b = blockIdx.x;
    const int tid = threadIdx.x;
    const int* cbase;
    int n, blk, outi;
    if (b < NBm) { cbase = cnt + (size_t)nu * CSTR; n = nm; blk = b; outi = b; }
    else         { cbase = cnt; n = nu; blk = b - NBm; outi = 64 + (b - NBm); }
    int base = blk * 4096 + tid * 16;
    int sum = 0;
#pragma unroll
    for (int k = 0; k < 16; ++k) {
        int i = base + k;
        if (i < n) sum += cbase[(size_t)i * CSTR];
    }
    s[tid] = sum;
    __syncthreads();
    for (int d = 128; d > 0; d >>= 1) {
        if (tid < d) s[tid] += s[tid + d];
        __syncthreads();
    }
    if (tid == 0) bsum[outi] = s[0];
}

__global__ __launch_bounds__(256)
void scan_apply2(const int* __restrict__ cnt, const int* __restrict__ bsum,
                 int* __restrict__ off, int nu, int nm, int NBm, int NBu,
                 int E) {
    __shared__ int s[256];
    __shared__ int sb[64];
    __shared__ int pfx;
    const int b = blockIdx.x;
    const int tid = threadIdx.x;
    const int* cbase;
    const int* bbase;
    int* obase;
    int n, nb, blk, addbase;
    if (b < NBm) {
        cbase = cnt + (size_t)nu * CSTR; bbase = bsum; obase = off + nu;
        n = nm; nb = NBm; blk = b; addbase = E;
    } else {
        cbase = cnt; bbase = bsum + 64; obase = off;
        n = nu; nb = NBu; blk = b - NBm; addbase = 0;
    }
    int base = blk * 4096 + tid * 16;
    int v[16];
    int sum = 0;
#pragma unroll
    for (int k = 0; k < 16; ++k) {
        int i = base + k;
        v[k] = (i < n) ? cbase[(size_t)i * CSTR] : 0;
        sum += v[k];
    }
    s[tid] = sum;
    if (tid < 64) sb[tid] = (tid < nb) ? bbase[tid] : 0;
    __syncthreads();
    for (int d = 1; d < 256; d <<= 1) {
        int t = (tid >= d) ? s[tid - d] : 0;
        __syncthreads();
        s[tid] += t;
        __syncthreads();
    }
    if (tid == 0) {
        int p = 0;
        for (int b2 = 0; b2 < blk; ++b2) p += sb[b2];
        pfx = p;
        if (blk == nb - 1) obase[n] = addbase + p + s[255];
    }
    __syncthreads();
    int run = addbase + pfx + s[tid] - sum;
#pragma unroll
    for (int k = 0; k < 16; ++k) {
        int i = base + k;
        if (i < n) obase[i] = run;
        run += v[k];
    }
}

// ============ K4: fill_m || conv (conv hides under scatter) ============
__global__ __launch_bounds__(256)
void fillm_conv(const int* __restrict__ src, const int* __restrict__ dst,
                const int* __restrict__ rankm, const int* __restrict__ off,
                int* __restrict__ nbr, int E, int nu, int egF,
                const float* __restrict__ xu, const float* __restrict__ xm,
                u32* __restrict__ xub, u32* __restrict__ xmb, int nm) {
    const int bid = blockIdx.x;
    const int tid = threadIdx.x;
    if (bid < egF) {
        // ---- fill_m: nbr[off[nu+d] + rankm[e]] = s ----
        const int e0 = bid * 1024 + tid;
        int sv[4], dv[4], rm[4];
#pragma unroll
        for (int k = 0; k < 4; ++k) {
            int e = e0 + k * 256;
            rm[k] = -1;
            if (e < E) {
                rm[k] = rankm[e];
                sv[k] = src[e]; dv[k] = dst[e];
            }
        }
#pragma unroll
        for (int k = 0; k < 4; ++k) {
            if (rm[k] >= 0) nbr[off[nu + dv[k]] + rm[k]] = sv[k];
        }
    } else {
        // ---- f32 [.][128] -> packed bf16 u32 [.][64]; 4 u32 per thread ----
        const int id = (bid - egF) * 1024 + tid * 4;
        const int nuc = nu * 64;
        const int tot = nuc + nm * 64;   // both multiples of 4: no straddle
        if (id < tot) {
            const float* fin;
            u32* fout;
            int rel;
            if (id < nuc) { fin = xu; fout = xub; rel = id; }
            else          { fin = xm; fout = xmb; rel = id - nuc; }
            float4 p0 = ((const float4*)fin)[(rel >> 1)];
            float4 p1 = ((const float4*)fin)[(rel >> 1) + 1];
            u32x4 o = { pack2bf(p0.x, p0.y), pack2bf(p0.z, p0.w),
                        pack2bf(p1.x, p1.y), pack2bf(p1.z, p1.w) };
            *(u32x4*)(fout + rel) = o;
        }
    }
}

// ================= fused gather-mean + MFMA node update =================
// (round-5 proven body: slot-parallel gather, 16 nodes/block, 2 waves)
template <int L1>
__device__ __forceinline__ void fused_body(
    const u32* __restrict__ featb, const float* __restrict__ xf,
    const u32* __restrict__ xb, const int* __restrict__ off,
    const int* __restrict__ nbr, const u16* __restrict__ wt,
    const float* __restrict__ bias, void* __restrict__ outp, int N, int blk) {
    __shared__ u32 sVb[16][132];     // bf16 pairs: k<128 mean, k>=128 x; pad 4
    const int tid = threadIdx.x;
    const int lane = tid & 63;
    const int wave = tid >> 6;       // 0..1
    const int base = blk * 16;
    const int q = lane >> 4;         // node slot (phase1) / D-row quad (phase2)
    const int cl = lane & 15;        // channel group (phase1) / D col (phase2)

    // ---- phase 1: slot-parallel gather-mean (2 quads of 4 nodes / wave) ----
#pragma unroll
    for (int gg = 0; gg < 2; ++gg) {
        const int i = wave * 8 + gg * 4 + q;   // node-local index 0..15
        const int n = base + i;
        int b = 0, e2 = 0;
        if (n < N) { b = off[n]; e2 = off[n + 1]; }
        const int deg = e2 - b;
        float a0 = 0.f, a1 = 0.f, a2 = 0.f, a3 = 0.f;
        float a4 = 0.f, a5 = 0.f, a6 = 0.f, a7 = 0.f;
        for (int j = 0; j < deg; j += 4) {
            const int p = b + j;
            const int p1 = (p + 1 < e2) ? p + 1 : e2 - 1;
            const int p2 = (p + 2 < e2) ? p + 2 : e2 - 1;
            const int p3 = (p + 3 < e2) ? p + 3 : e2 - 1;
            const float m1 = (p + 1 < e2) ? 1.f : 0.f;
            const float m2 = (p + 2 < e2) ? 1.f : 0.f;
            const float m3 = (p + 3 < e2) ? 1.f : 0.f;
            const int g0 = nbr[p];
            const int g1 = nbr[p1];
            const int g2 = nbr[p2];
            const int g3 = nbr[p3];
            u32x4 v0 = *(const u32x4*)(featb + (size_t)g0 * 64 + cl * 4);
            u32x4 v1 = *(const u32x4*)(featb + (size_t)g1 * 64 + cl * 4);
            u32x4 v2 = *(const u32x4*)(featb + (size_t)g2 * 64 + cl * 4);
            u32x4 v3 = *(const u32x4*)(featb + (size_t)g3 * 64 + cl * 4);
            a0 += bflo(v0.x); a1 += bfhi(v0.x); a2 += bflo(v0.y); a3 += bfhi(v0.y);
            a4 += bflo(v0.z); a5 += bfhi(v0.z); a6 += bflo(v0.w); a7 += bfhi(v0.w);
            a0 = fmaf(bflo(v1.x), m1, a0); a1 = fmaf(bfhi(v1.x), m1, a1);
            a2 = fmaf(bflo(v1.y), m1, a2); a3 = fmaf(bfhi(v1.y), m1, a3);
            a4 = fmaf(bflo(v1.z), m1, a4); a5 = fmaf(bfhi(v1.z), m1, a5);
            a6 = fmaf(bflo(v1.w), m1, a6); a7 = fmaf(bfhi(v1.w), m1, a7);
            a0 = fmaf(bflo(v2.x), m2, a0); a1 = fmaf(bfhi(v2.x), m2, a1);
            a2 = fmaf(bflo(v2.y), m2, a2); a3 = fmaf(bfhi(v2.y), m2, a3);
            a4 = fmaf(bflo(v2.z), m2, a4); a5 = fmaf(bfhi(v2.z), m2, a5);
            a6 = fmaf(bflo(v2.w), m2, a6); a7 = fmaf(bfhi(v2.w), m2, a7);
            a0 = fmaf(bflo(v3.x), m3, a0); a1 = fmaf(bfhi(v3.x), m3, a1);
            a2 = fmaf(bflo(v3.y), m3, a2); a3 = fmaf(bfhi(v3.y), m3, a3);
            a4 = fmaf(bflo(v3.z), m3, a4); a5 = fmaf(bfhi(v3.z), m3, a5);
            a6 = fmaf(bflo(v3.w), m3, a6); a7 = fmaf(bfhi(v3.w), m3, a7);
        }
        const float inv = 1.0f / (float)(deg > 1 ? deg : 1);
        u32x4 o = { pack2bf(a0 * inv, a1 * inv), pack2bf(a2 * inv, a3 * inv),
                    pack2bf(a4 * inv, a5 * inv), pack2bf(a6 * inv, a7 * inv) };
        *(u32x4*)&sVb[i][cl * 4] = o;     // slot's 16 lanes = full 256B row
    }
    // ---- x staging (full-wave coalesced rows, 8 nodes/wave) ----
    for (int c = 0; c < 8; ++c) {
        const int i = wave * 8 + c;
        const int n = base + i;
        if (n < N) {
            if (L1) {
                const float2 xv = ((const float2*)xf)[(size_t)n * 64 + lane];
                sVb[i][64 + lane] = pack2bf(xv.x, xv.y);
            } else {
                sVb[i][64 + lane] = xb[(size_t)n * 64 + lane];
            }
        } else {
            sVb[i][64 + lane] = 0u;
        }
    }
    __syncthreads();

    // ---- phase 2: MFMA GEMM (16 nodes x 256 K x 128 out), 4 tiles/wave ----
    const int t0 = wave * 4;
    const u16* sVbu = (const u16*)sVb;  // row stride 264 ushort (528 B)
    const short8* wtp = (const short8*)wt;

    f32x4 acc0 = {0.f, 0.f, 0.f, 0.f};
    f32x4 acc1 = {0.f, 0.f, 0.f, 0.f};
    f32x4 acc2 = {0.f, 0.f, 0.f, 0.f};
    f32x4 acc3 = {0.f, 0.f, 0.f, 0.f};
#pragma unroll
    for (int s = 0; s < 8; ++s) {
        short8 a = *(const short8*)(sVbu + (size_t)cl * 264 + s * 32 + q * 8);
        short8 b0 = wtp[(size_t)((t0 + 0) * 8 + s) * 64 + lane];
        short8 b1 = wtp[(size_t)((t0 + 1) * 8 + s) * 64 + lane];
        short8 b2 = wtp[(size_t)((t0 + 2) * 8 + s) * 64 + lane];
        short8 b3 = wtp[(size_t)((t0 + 3) * 8 + s) * 64 + lane];
        acc0 = __builtin_amdgcn_mfma_f32_16x16x32_bf16(a, b0, acc0, 0, 0, 0);
        acc1 = __builtin_amdgcn_mfma_f32_16x16x32_bf16(a, b1, acc1, 0, 0, 0);
        acc2 = __builtin_amdgcn_mfma_f32_16x16x32_bf16(a, b2, acc2, 0, 0, 0);
        acc3 = __builtin_amdgcn_mfma_f32_16x16x32_bf16(a, b3, acc3, 0, 0, 0);
    }

    // ---- epilogue: D[m][n], col=lane&15, row=quad*4+reg ----
#pragma unroll
    for (int tt = 0; tt < 4; ++tt) {
        const f32x4& cc = tt == 0 ? acc0 : tt == 1 ? acc1 : tt == 2 ? acc2 : acc3;
        const int nn = (t0 + tt) * 16 + cl;
        const float bj = bias[nn];
#pragma unroll
        for (int r = 0; r < 4; ++r) {
            const int m = q * 4 + r;
            const int node = base + m;
            if (node < N) {
                float h = cc[r] + bj;
                if (L1) {
                    u16* ob = (u16*)outp;
                    float x0 = xf[(size_t)node * 128 + nn];   // L1-hot reload
                    ob[(size_t)node * 128 + nn] = f2bf(x0 + fmaxf(h, 0.f));
                } else {
                    float* o = (float*)outp;
                    o[(size_t)node * 128 + nn] = h;
                }
            }
        }
    }
}

// ======================= K5: l1_movie || fill_u =======================
// Blocks [0,gm): L1 movie update (gathers xu_bf via movie CSR, writes rm_bf).
// Blocks [gm,gm+egF): fill_u (user nbr segments; hides under the gather).
// Disjoint nbr ranges: movie segs [E,2E) read, user segs [0,E) written.
__global__ __launch_bounds__(128, 8)
void l1movie_fillu(const u32* __restrict__ Abf, const float* __restrict__ xm,
                   const int* __restrict__ off, const int* __restrict__ nbr_r,
                   const u16* __restrict__ wt, const float* __restrict__ bias,
                   void* __restrict__ outp, int nm, int nu, int gm,
                   const int* __restrict__ src, const int* __restrict__ dst,
                   const int* __restrict__ ranku, int* __restrict__ nbr_w,
                   int E) {
    if ((int)blockIdx.x < gm) {
        fused_body<1>(Abf, xm, nullptr, off + nu, nbr_r, wt, bias, outp, nm,
                      blockIdx.x);
    } else {
        const int e0 = ((int)blockIdx.x - gm) * 1024 + (int)threadIdx.x;
        int sv[8], dv[8], ru[8];
#pragma unroll
        for (int k = 0; k < 8; ++k) {
            int e = e0 + k * 128;
            ru[k] = -1;
            if (e < E) {
                ru[k] = ranku[e];
                sv[k] = src[e]; dv[k] = dst[e];
            }
        }
#pragma unroll
        for (int k = 0; k < 8; ++k) {
            if (ru[k] >= 0) nbr_w[off[sv[k]] + ru[k]] = dv[k];
        }
    }
}

__global__ __launch_bounds__(128, 8)
void fused_l1(const u32* __restrict__ featb, const float* __restrict__ xf,
              const int* __restrict__ off, const int* __restrict__ nbr,
              const u16* __restrict__ wt, const float* __restrict__ bias,
              void* __restrict__ outp, int N) {
    fused_body<1>(featb, xf, nullptr, off, nbr, wt, bias, outp, N, blockIdx.x);
}

// Layer-2 pair merged (no aliasing: reads Abf+rmb only, writes d_out only).
__global__ __launch_bounds__(128, 8)
void fused_l2_dual(const u32* __restrict__ Abf, const u32* __restrict__ rmb,
                   const int* __restrict__ off, const int* __restrict__ nbr,
                   const u16* __restrict__ wtm, const u16* __restrict__ wtu,
                   const float* __restrict__ bm, const float* __restrict__ bu,
                   float* __restrict__ outm, float* __restrict__ outu,
                   int nm, int nu, int gm) {
    if ((int)blockIdx.x < gm)
        fused_body<0>(Abf, nullptr, rmb, off + nu, nbr, wtm, bm, outm, nm,
                      blockIdx.x);
    else
        fused_body<0>(rmb, nullptr, Abf, off, nbr, wtu, bu, outu, nu,
                      blockIdx.x - gm);
}

extern "C" void kernel_launch(void* const* d_in, const int* in_sizes, int n_in,
                              void* d_out, int out_size, void* d_ws, size_t ws_size,
                              hipStream_t stream) {
    const int nu = in_sizes[0] / 128;
    const int nm = in_sizes[1] / 128;
    const int E = in_sizes[2];

    const float* xu = (const float*)d_in[0];
    const float* xm = (const float*)d_in[1];
    const int* esrc = (const int*)d_in[2];
    const int* edst = (const int*)d_in[3];
    const float* Wl1_um = (const float*)d_in[4];
    const float* Wr1_um = (const float*)d_in[5];
    const float* Wl1_mu = (const float*)d_in[6];
    const float* Wr1_mu = (const float*)d_in[7];
    const float* Wl2_um = (const float*)d_in[8];
    const float* Wr2_um = (const float*)d_in[9];
    const float* Wl2_mu = (const float*)d_in[10];
    const float* Wr2_mu = (const float*)d_in[11];
    const float* b1_um = (const float*)d_in[12];
    const float* b1_mu = (const float*)d_in[13];
    const float* b2_um = (const float*)d_in[14];
    const float* b2_mu = (const float*)d_in[15];

    float* out_u = (float*)d_out;
    float* out_m = out_u + (size_t)nu * 128;

    // ---- workspace layout (~56.5 MB; >=62 MB available) ----
    const int ntot = nu + nm;
    int* cnt = (int*)d_ws;                     // ntot * CSTR (32B-padded)
    int* off = cnt + (size_t)ntot * CSTR;      // ntot+1
    int* bsum = off + ntot + 1;                // 128 (movie@0, user@64)
    int* ranku = bsum + 128;                   // E
    int* rankm = ranku + E;                    // E
    int* nbr = rankm + E;                      // 2E
    size_t int_bytes = (size_t)((nbr + 2 * (size_t)E) - (int*)d_ws) * 4;
    size_t wt_off = (int_bytes + 63) & ~(size_t)63;   // 16B-align for short8
    u16* wt1_um = (u16*)((char*)d_ws + wt_off);       // 4 stacks x 32768 u16
    u16* wt1_mu = wt1_um + 32768;
    u16* wt2_um = wt1_mu + 32768;
    u16* wt2_mu = wt2_um + 32768;
    // bf16 feature buffers. Abf holds xu_bf for layer 1, then is overwritten
    // with ru_bf by the L1-user dispatch (xu_bf's last consumer, L1-movie,
    // completes first in stream order).
    u32* Abf = (u32*)((char*)d_ws + wt_off + 4 * 65536);  // nu*64
    u32* xmb = Abf + (size_t)nu * 64;                     // nm*64
    u32* rmb = xmb + (size_t)nm * 64;                     // nm*64

    const int egH = (E + 1023) / 1024;         // 256-thr, 4 edges/thread
    const int egF = (E + 1023) / 1024;
    const int cg = (ntot * 64 + 1023) / 1024;
    const int NBm = (nm + 4095) / 4096;        // <=64
    const int NBu = (nu + 4095) / 4096;        // <=64

    WPtrs wp;
    wp.wl[0] = Wl1_um; wp.wr[0] = Wr1_um; wp.wout[0] = wt1_um;
    wp.wl[1] = Wl1_mu; wp.wr[1] = Wr1_mu; wp.wout[1] = wt1_mu;
    wp.wl[2] = Wl2_um; wp.wr[2] = Wr2_um; wp.wout[2] = wt2_um;
    wp.wl[3] = Wl2_mu; wp.wr[3] = Wr2_mu; wp.wout[3] = wt2_mu;

    const int gm = (nm + 15) / 16;
    const int gu = (nu + 15) / 16;

    // ---- pipeline (round-8): conv moved under fill_m; scans fused ----
    hipMemsetAsync(cnt, 0, (size_t)ntot * CSTR * 4, stream);
    // K1: both-dir hist+rank || wprep
    hist_wprep<<<egH + 64, 256, 0, stream>>>(
        esrc, edst, cnt, ranku, rankm, E, nu, nm, egH, wp);
    // K2/K3: fused scans (movie -> off[nu..], base E; user -> off[0..nu])
    scan_partial2<<<NBm + NBu, 256, 0, stream>>>(cnt, bsum, nu, nm, NBm);
    scan_apply2<<<NBm + NBu, 256, 0, stream>>>(cnt, bsum, off, nu, nm,
                                               NBm, NBu, E);
    // K4: fill_m || conv (streaming conv hides under scatter)
    fillm_conv<<<egF + cg, 256, 0, stream>>>(
        esrc, edst, rankm, off, nbr, E, nu, egF, xu, xm, Abf, xmb, nm);
    // K5: l1_movie (gather xu_bf -> rm_bf) || fill_u
    l1movie_fillu<<<gm + egF, 128, 0, stream>>>(
        Abf, xm, off, nbr, wt1_um, b1_um, rmb, nm, nu, gm,
        esrc, edst, ranku, nbr, E);
    // K6: l1_user (gather xm_bf, x=xu, write ru_bf into Abf; xu_bf dead)
    fused_l1<<<gu, 128, 0, stream>>>(xmb, xu, off, nbr, wt1_mu, b1_mu,
                                     Abf, nu);
    // K7: layer 2 merged (reads Abf/rmb only; writes d_out only)
    fused_l2_dual<<<gm + gu, 128, 0, stream>>>(
        Abf, rmb, off, nbr, wt2_um, wt2_mu, b2_um, b2_mu, out_m, out_u,
        nm, nu, gm);
}